// Round 9
// baseline (275.064 us; speedup 1.0000x reference)
//
#include <hip/hip_runtime.h>
#include <math.h>

// SPINN thin-stack encoder, B=64, L=128, D=128, T=255.
// Phase A (parallel): G[b,l,:] = buf[b,l,:] @ Wr  for every token.
// Phase B (sequential): ONE WAVE (64 threads) per example; lane d owns
//   output columns d and d+64 (float2 weights/accs -> v_pk_fma_f32 chance).
//   Single-wave => NO __syncthreads in the 255-step loop (same-wave LDS
//   RAW ordered by lgkmcnt), and the left-row LDS broadcast is read ONCE
//   and reused for both columns. Loads stay address-space-clean (global
//   vs LDS loops split by uniform branch -- no flat loads).

namespace {

constexpr int kB = 64;
constexpr int kL = 128;
constexpr int kD = 128;
constexpr int kT = 2 * kL - 1;          // 255
constexpr int kTPad = 256;              // padded transitions (tail = SKIP)
constexpr int kSlots = 160;             // fresh LDS slot per reduce (127 used)
constexpr unsigned kRecZero = 0xFFFFFFFFu;
constexpr unsigned kRecTok = 0x80000000u;
constexpr unsigned kMask = 0x7FFFFFFFu;
constexpr int kRowsPerBlk = 16;

// ---------------------------------------------------------------------------
// Phase A: G = buf @ Wr.  grid = B*L/kRowsPerBlk x 128 threads.
// ---------------------------------------------------------------------------
__global__ __launch_bounds__(128, 1) void precomp_wr_kernel(
    const float* __restrict__ buf, const float* __restrict__ Wr,
    float* __restrict__ G) {
  __shared__ float rows[kRowsPerBlk][kD];
  const int d = threadIdx.x;
  const long row0 = (long)blockIdx.x * kRowsPerBlk;

  float w[kD];
#pragma unroll
  for (int k = 0; k < kD; ++k) w[k] = Wr[k * kD + d];

  const float* src = buf + row0 * kD;
#pragma unroll
  for (int i = 0; i < kRowsPerBlk; ++i) rows[i][d] = src[i * kD + d];
  __syncthreads();

#pragma unroll
  for (int r = 0; r < kRowsPerBlk; ++r) {
    float a0 = 0.f, a1 = 0.f, a2 = 0.f, a3 = 0.f;
#pragma unroll
    for (int k4 = 0; k4 < kD / 4; ++k4) {
      const float4 x = *reinterpret_cast<const float4*>(&rows[r][k4 * 4]);
      a0 = fmaf(x.x, w[k4 * 4 + 0], a0);
      a1 = fmaf(x.y, w[k4 * 4 + 1], a1);
      a2 = fmaf(x.z, w[k4 * 4 + 2], a2);
      a3 = fmaf(x.w, w[k4 * 4 + 3], a3);
    }
    G[(row0 + r) * kD + d] = (a0 + a1) + (a2 + a3);
  }
}

__device__ __forceinline__ float fast_tanh(float x) {
  // tanh(x) = 1 - 2*rcp(e^{2x}+1); v_exp_f32 + v_rcp_f32, no div sequence.
  const float e = __expf(2.0f * x);
  return 1.0f - 2.0f * __builtin_amdgcn_rcpf(e + 1.0f);
}

// 8 k-values (xa,xb) feed both columns: 16 fma, chains l0..l7 (float2).
#define FMA8(xa, xb, kb)                                                     \
  l0.x = fmaf((xa).x, wl2[(kb) + 0].x, l0.x);                                \
  l0.y = fmaf((xa).x, wl2[(kb) + 0].y, l0.y);                                \
  l1.x = fmaf((xa).y, wl2[(kb) + 1].x, l1.x);                                \
  l1.y = fmaf((xa).y, wl2[(kb) + 1].y, l1.y);                                \
  l2.x = fmaf((xa).z, wl2[(kb) + 2].x, l2.x);                                \
  l2.y = fmaf((xa).z, wl2[(kb) + 2].y, l2.y);                                \
  l3.x = fmaf((xa).w, wl2[(kb) + 3].x, l3.x);                                \
  l3.y = fmaf((xa).w, wl2[(kb) + 3].y, l3.y);                                \
  l4.x = fmaf((xb).x, wl2[(kb) + 4].x, l4.x);                                \
  l4.y = fmaf((xb).x, wl2[(kb) + 4].y, l4.y);                                \
  l5.x = fmaf((xb).y, wl2[(kb) + 5].x, l5.x);                                \
  l5.y = fmaf((xb).y, wl2[(kb) + 5].y, l5.y);                                \
  l6.x = fmaf((xb).z, wl2[(kb) + 6].x, l6.x);                                \
  l6.y = fmaf((xb).z, wl2[(kb) + 6].y, l6.y);                                \
  l7.x = fmaf((xb).w, wl2[(kb) + 7].x, l7.x);                                \
  l7.y = fmaf((xb).w, wl2[(kb) + 7].y, l7.y);

// ---------------------------------------------------------------------------
// Phase B: grid = 64 blocks x 64 threads (1 wave). Lane d -> cols d, d+64.
// LDS: gl (64KB) staged G rows; stk (80KB) composed vectors, fresh slot per
// reduce; tlds transitions; deep = record mirror (replicated writes, single
// wave -> trivially consistent). No barriers in the main loop.
// ---------------------------------------------------------------------------
template <bool USE_G>
__global__ __launch_bounds__(64, 1) void spinn_kernel(
    const float* __restrict__ buf, const float* __restrict__ Wl,
    const float* __restrict__ Wr, const float* __restrict__ bias,
    const int* __restrict__ trans, const float* __restrict__ G,
    float* __restrict__ out) {
  __shared__ float gl[kL][kD];        // 65536 B
  __shared__ float stk[kSlots][kD];   // 81920 B
  __shared__ int tlds[kTPad];         // 1024 B
  __shared__ unsigned deep[kT + 8];   // record mirror

  const int b = blockIdx.x;
  const int d = threadIdx.x;  // 0..63

  // Wl columns d and d+64 -> float2-packed registers.
  float2 wl2[kD];
#pragma unroll
  for (int k = 0; k < kD; ++k) {
    wl2[k].x = Wl[k * kD + d];
    wl2[k].y = Wl[k * kD + d + 64];
  }
  const float bv0 = bias[d];
  const float bv1 = bias[d + 64];

  for (int t = d; t < kTPad; t += 64) tlds[t] = (t < kT) ? trans[b * kT + t] : 2;
  deep[0] = kRecZero;
  deep[1] = kRecZero;

  const float* bufb = buf + (long)b * kL * kD;

  // Stage this example's G into LDS (64 KB, coalesced float4).
  if (USE_G) {
    const float4* g4 = reinterpret_cast<const float4*>(G + (long)b * kL * kD);
    float4* l4p = reinterpret_cast<float4*>(&gl[0][0]);
#pragma unroll
    for (int i = 0; i < (kL * kD / 4) / 64; ++i) l4p[i * 64 + d] = g4[i * 64 + d];
  }
  __syncthreads();  // one-time; single wave, essentially free

  unsigned r0 = kRecZero, r1 = kRecZero, r2 = kRecZero;
  int sp = 2, bp = 0, nxt = 0;

  int4 cur = *reinterpret_cast<const int4*>(&tlds[0]);
  for (int c = 0; c < kTPad / 4; ++c) {
    int4 nxtv;  // prefetch next transition chunk
    if (c < kTPad / 4 - 1)
      nxtv = *reinterpret_cast<const int4*>(&tlds[(c + 1) * 4]);
    else
      nxtv = make_int4(2, 2, 2, 2);

    const int trs[4] = {cur.x, cur.y, cur.z, cur.w};
#pragma unroll
    for (int j = 0; j < 4; ++j) {
      const int tr = trs[j];
      if (tr == 0) {
        // ---- SHIFT: record bookkeeping only ----
        const unsigned tokRec = kRecTok | (unsigned)min(bp, kL - 1);
        deep[sp] = tokRec;
        r2 = r1;
        r1 = r0;
        r0 = tokRec;
        ++sp;
        ++bp;
      } else if (tr == 1) {
        // ---- REDUCE ----
        const unsigned refill = deep[max(sp - 4, 0)];  // early refill

        float a0 = bv0, a1 = bv1;

        // Right operand = r0 (top). Hot: token -> LDS-staged G row.
        if (__builtin_expect(r0 != kRecZero, 1)) {
          if (__builtin_expect((r0 & kRecTok) != 0, 1)) {
            const int tok = (int)(r0 & kMask);
            if (USE_G) {
              a0 += gl[tok][d];
              a1 += gl[tok][d + 64];
            } else {
              const float* __restrict__ v = bufb + (long)tok * kD;
              for (int k = 0; k < kD; ++k) {
                a0 = fmaf(v[k], Wr[k * kD + d], a0);
                a1 = fmaf(v[k], Wr[k * kD + d + 64], a1);
              }
            }
          } else {  // cold: composed right
            const int row = (int)r0;
            for (int k = 0; k < kD; ++k) {
              a0 = fmaf(stk[row][k], Wr[k * kD + d], a0);
              a1 = fmaf(stk[row][k], Wr[k * kD + d + 64], a1);
            }
          }
        }

        // Left operand = r1: the recurrence. Row read ONCE, feeds both
        // columns. Address-space-clean loops (no flat loads).
        float2 l0{0, 0}, l1{0, 0}, l2{0, 0}, l3{0, 0};
        float2 l4{0, 0}, l5{0, 0}, l6{0, 0}, l7{0, 0};
        if (__builtin_expect(r1 != kRecZero, 1)) {
          if (r1 & kRecTok) {
            const float* __restrict__ v = bufb + (long)(r1 & kMask) * kD;
#pragma unroll
            for (int k8 = 0; k8 < kD / 8; ++k8) {
              const float4 xa = *reinterpret_cast<const float4*>(v + k8 * 8);
              const float4 xb = *reinterpret_cast<const float4*>(v + k8 * 8 + 4);
              FMA8(xa, xb, k8 * 8)
            }
          } else {
            const int row = (int)r1;
#pragma unroll
            for (int k8 = 0; k8 < kD / 8; ++k8) {
              const float4 xa =
                  *reinterpret_cast<const float4*>(&stk[row][k8 * 8]);
              const float4 xb =
                  *reinterpret_cast<const float4*>(&stk[row][k8 * 8 + 4]);
              FMA8(xa, xb, k8 * 8)
            }
          }
        }
        a0 += (((l0.x + l1.x) + (l2.x + l3.x)) + ((l4.x + l5.x) + (l6.x + l7.x)));
        a1 += (((l0.y + l1.y) + (l2.y + l3.y)) + ((l4.y + l5.y) + (l6.y + l7.y)));

        const float y0 = fast_tanh(a0);
        const float y1 = fast_tanh(a1);

        const int slot = nxt;  // fresh slot; never aliases a live read
        ++nxt;
        if (nxt == kSlots) nxt = 0;
        stk[slot][d] = y0;
        stk[slot][d + 64] = y1;

        deep[sp - 2] = (unsigned)slot;
        --sp;
        r0 = (unsigned)slot;
        r1 = r2;
        r2 = refill;
        // Single wave: same-wave LDS RAW ordered by lgkmcnt -- NO barrier.
      }
      // tr == 2 (SKIP): no-op.
    }
    cur = nxtv;
  }

  float o0 = 0.f, o1 = 0.f;
  if (r0 != kRecZero) {
    if (r0 & kRecTok) {
      const long tok = (long)(r0 & kMask);
      o0 = bufb[tok * kD + d];
      o1 = bufb[tok * kD + d + 64];
    } else {
      o0 = stk[(int)r0][d];
      o1 = stk[(int)r0][d + 64];
    }
  }
  out[(long)b * kD + d] = o0;
  out[(long)b * kD + d + 64] = o1;
}

}  // namespace

extern "C" void kernel_launch(void* const* d_in, const int* in_sizes, int n_in,
                              void* d_out, int out_size, void* d_ws,
                              size_t ws_size, hipStream_t stream) {
  const float* buf = (const float*)d_in[0];
  const float* Wl = (const float*)d_in[1];
  const float* Wr = (const float*)d_in[2];
  const float* bias = (const float*)d_in[3];
  const int* trans = (const int*)d_in[4];
  float* out = (float*)d_out;

  const size_t gbytes = (size_t)kB * kL * kD * sizeof(float);
  if (ws_size >= gbytes) {
    float* G = (float*)d_ws;
    precomp_wr_kernel<<<dim3(kB * kL / kRowsPerBlk), dim3(128), 0, stream>>>(
        buf, Wr, G);
    spinn_kernel<true><<<dim3(kB), dim3(64), 0, stream>>>(buf, Wl, Wr, bias,
                                                          trans, G, out);
  } else {
    spinn_kernel<false><<<dim3(kB), dim3(64), 0, stream>>>(
        buf, Wl, Wr, bias, trans, nullptr, out);
  }
}

// Round 10
// 165.786 us; speedup vs baseline: 1.6591x; 1.6591x over previous
//
#include <hip/hip_runtime.h>
#include <math.h>

// SPINN thin-stack encoder, B=64, L=128, D=128, T=255.
// Phase A (parallel): G[b,l,:] = buf[b,l,:] @ Wr  for every token.
// Phase B (sequential, 1 block/example, 128 thr = 2 waves, 1 col/lane).
//   THIS ROUND'S SINGLE CHANGE vs the 103us R7 kernel: Wl column weights
//   are 128 individually-NAMED const float scalars (macro-generated), not
//   a float[128] array. Evidence (R7 vs R9): per-lane weight count doubled
//   -> time doubled while LDS reads halved => weights were being
//   remat-loaded/spilled every step (VGPR_Count stuck at 132/152). Named
//   SSA scalars are the strongest register-promotion form.

namespace {

constexpr int kB = 64;
constexpr int kL = 128;
constexpr int kD = 128;
constexpr int kT = 2 * kL - 1;          // 255
constexpr int kTPad = 256;              // padded transitions (tail = SKIP)
constexpr int kSlots = 160;             // fresh LDS slot per reduce (127 used)
constexpr unsigned kRecZero = 0xFFFFFFFFu;
constexpr unsigned kRecTok = 0x80000000u;
constexpr unsigned kMask = 0x7FFFFFFFu;
constexpr int kRowsPerBlk = 16;

// ---------------------------------------------------------------------------
// Phase A: G = buf @ Wr.  grid = B*L/kRowsPerBlk x 128 threads.
// ---------------------------------------------------------------------------
__global__ __launch_bounds__(128, 1) void precomp_wr_kernel(
    const float* __restrict__ buf, const float* __restrict__ Wr,
    float* __restrict__ G) {
  __shared__ float rows[kRowsPerBlk][kD];
  const int d = threadIdx.x;
  const long row0 = (long)blockIdx.x * kRowsPerBlk;

  float w[kD];
#pragma unroll
  for (int k = 0; k < kD; ++k) w[k] = Wr[k * kD + d];

  const float* src = buf + row0 * kD;
#pragma unroll
  for (int i = 0; i < kRowsPerBlk; ++i) rows[i][d] = src[i * kD + d];
  __syncthreads();

#pragma unroll
  for (int r = 0; r < kRowsPerBlk; ++r) {
    float a0 = 0.f, a1 = 0.f, a2 = 0.f, a3 = 0.f;
#pragma unroll
    for (int k4 = 0; k4 < kD / 4; ++k4) {
      const float4 x = *reinterpret_cast<const float4*>(&rows[r][k4 * 4]);
      a0 = fmaf(x.x, w[k4 * 4 + 0], a0);
      a1 = fmaf(x.y, w[k4 * 4 + 1], a1);
      a2 = fmaf(x.z, w[k4 * 4 + 2], a2);
      a3 = fmaf(x.w, w[k4 * 4 + 3], a3);
    }
    G[(row0 + r) * kD + d] = (a0 + a1) + (a2 + a3);
  }
}

__device__ __forceinline__ float fast_tanh(float x) {
  // tanh(x) = 1 - 2*rcp(e^{2x}+1)
  const float e = __expf(2.0f * x);
  return 1.0f - 2.0f * __builtin_amdgcn_rcpf(e + 1.0f);
}

// ---- 128 named weight scalars, 16 groups of 8 -----------------------------
#define DEF_WGRP(g)                                                          \
  const float w_##g##_0 = Wl[((g)*8 + 0) * kD + d];                          \
  const float w_##g##_1 = Wl[((g)*8 + 1) * kD + d];                          \
  const float w_##g##_2 = Wl[((g)*8 + 2) * kD + d];                          \
  const float w_##g##_3 = Wl[((g)*8 + 3) * kD + d];                          \
  const float w_##g##_4 = Wl[((g)*8 + 4) * kD + d];                          \
  const float w_##g##_5 = Wl[((g)*8 + 5) * kD + d];                          \
  const float w_##g##_6 = Wl[((g)*8 + 6) * kD + d];                          \
  const float w_##g##_7 = Wl[((g)*8 + 7) * kD + d];

#define FMA_GRP(g, xa, xb)                                                   \
  l0 = fmaf((xa).x, w_##g##_0, l0);                                          \
  l1 = fmaf((xa).y, w_##g##_1, l1);                                          \
  l2 = fmaf((xa).z, w_##g##_2, l2);                                          \
  l3 = fmaf((xa).w, w_##g##_3, l3);                                          \
  l4 = fmaf((xb).x, w_##g##_4, l4);                                          \
  l5 = fmaf((xb).y, w_##g##_5, l5);                                          \
  l6 = fmaf((xb).z, w_##g##_6, l6);                                          \
  l7 = fmaf((xb).w, w_##g##_7, l7);

#define LEFT_GLOBAL_GRP(g)                                                   \
  {                                                                          \
    const float4 xa = *reinterpret_cast<const float4*>(v + (g)*8);           \
    const float4 xb = *reinterpret_cast<const float4*>(v + (g)*8 + 4);       \
    FMA_GRP(g, xa, xb)                                                       \
  }

#define LEFT_LDS_GRP(g)                                                      \
  {                                                                          \
    const float4 xa = *reinterpret_cast<const float4*>(&stk[row][(g)*8]);    \
    const float4 xb = *reinterpret_cast<const float4*>(&stk[row][(g)*8 + 4]);\
    FMA_GRP(g, xa, xb)                                                       \
  }

#define ALL16(M) \
  M(0) M(1) M(2) M(3) M(4) M(5) M(6) M(7) \
  M(8) M(9) M(10) M(11) M(12) M(13) M(14) M(15)

// ---------------------------------------------------------------------------
// Phase B: grid = 64 blocks x 128 threads (2 waves). Lane d -> column d.
// LDS: gl (64KB) staged G rows; stk (80KB) composed vectors (fresh slot per
// reduce); tlds transitions; deep = record mirror (replicated writes).
// Records: kRecZero | (kRecTok|tokidx) | composed slot index.
// ---------------------------------------------------------------------------
template <bool USE_G>
__global__ __launch_bounds__(128, 1) void spinn_kernel(
    const float* __restrict__ buf, const float* __restrict__ Wl,
    const float* __restrict__ Wr, const float* __restrict__ bias,
    const int* __restrict__ trans, const float* __restrict__ G,
    float* __restrict__ out) {
  __shared__ float gl[kL][kD];        // 65536 B
  __shared__ float stk[kSlots][kD];   // 81920 B
  __shared__ int tlds[kTPad];         // 1024 B
  __shared__ unsigned deep[kT + 8];   // record mirror

  const int b = blockIdx.x;
  const int d = threadIdx.x;

  // 128 NAMED weight scalars (the single change vs the 103us kernel).
  ALL16(DEF_WGRP)
  const float bv = bias[d];

  for (int t = d; t < kTPad; t += 128) tlds[t] = (t < kT) ? trans[b * kT + t] : 2;
  deep[0] = kRecZero;
  deep[1] = kRecZero;

  const float* bufb = buf + (long)b * kL * kD;

  // Stage this example's G into LDS (64 KB, coalesced float4).
  if (USE_G) {
    const float4* g4 = reinterpret_cast<const float4*>(G + (long)b * kL * kD);
    float4* l4p = reinterpret_cast<float4*>(&gl[0][0]);
#pragma unroll
    for (int i = 0; i < (kL * kD / 4) / 128; ++i) l4p[i * 128 + d] = g4[i * 128 + d];
  }
  __syncthreads();

  unsigned r0 = kRecZero, r1 = kRecZero, r2 = kRecZero;
  int sp = 2, bp = 0, nxt = 0;

  int4 cur = *reinterpret_cast<const int4*>(&tlds[0]);
  for (int c = 0; c < kTPad / 4; ++c) {
    int4 nxtv;  // prefetch next transition chunk
    if (c < kTPad / 4 - 1)
      nxtv = *reinterpret_cast<const int4*>(&tlds[(c + 1) * 4]);
    else
      nxtv = make_int4(2, 2, 2, 2);

    const int trs[4] = {cur.x, cur.y, cur.z, cur.w};
#pragma unroll
    for (int j = 0; j < 4; ++j) {
      const int tr = trs[j];
      if (tr == 0) {
        // ---- SHIFT: record bookkeeping only ----
        const unsigned tokRec = kRecTok | (unsigned)min(bp, kL - 1);
        deep[sp] = tokRec;
        r2 = r1;
        r1 = r0;
        r0 = tokRec;
        ++sp;
        ++bp;
      } else if (tr == 1) {
        // ---- REDUCE ----
        const unsigned refill = deep[max(sp - 4, 0)];  // early refill

        float acc = bv;

        // Right operand = r0 (top). Hot: token -> LDS-staged G row.
        if (__builtin_expect(r0 != kRecZero, 1)) {
          if (__builtin_expect((r0 & kRecTok) != 0, 1)) {
            const int tok = (int)(r0 & kMask);
            if (USE_G) {
              acc += gl[tok][d];
            } else {
              const float* __restrict__ vv = bufb + (long)tok * kD;
              for (int k = 0; k < kD; ++k)
                acc = fmaf(vv[k], Wr[k * kD + d], acc);
            }
          } else {  // cold: composed right
            const int row = (int)r0;
            for (int k = 0; k < kD; ++k)
              acc = fmaf(stk[row][k], Wr[k * kD + d], acc);
          }
        }

        // Left operand = r1: the recurrence. 8 acc chains, named weights,
        // address-space-clean paths (no flat loads).
        float l0 = 0.f, l1 = 0.f, l2 = 0.f, l3 = 0.f;
        float l4 = 0.f, l5 = 0.f, l6 = 0.f, l7 = 0.f;
        if (__builtin_expect(r1 != kRecZero, 1)) {
          if (r1 & kRecTok) {
            const float* __restrict__ v = bufb + (long)(r1 & kMask) * kD;
            ALL16(LEFT_GLOBAL_GRP)
          } else {
            const int row = (int)r1;
            ALL16(LEFT_LDS_GRP)
          }
        }
        acc += (((l0 + l1) + (l2 + l3)) + ((l4 + l5) + (l6 + l7)));

        const float y = fast_tanh(acc);

        const int slot = nxt;  // fresh slot; never aliases a live read
        ++nxt;
        if (nxt == kSlots) nxt = 0;
        stk[slot][d] = y;

        deep[sp - 2] = (unsigned)slot;
        --sp;
        r0 = (unsigned)slot;
        r1 = r2;
        r2 = refill;
        __syncthreads();  // publish stk[slot] across the 2 waves
      }
      // tr == 2 (SKIP): no-op.
    }
    cur = nxtv;
  }

  float o = 0.f;
  if (r0 != kRecZero) {
    if (r0 & kRecTok)
      o = bufb[(long)(r0 & kMask) * kD + d];
    else
      o = stk[(int)r0][d];
  }
  out[(long)b * kD + d] = o;
}

}  // namespace

extern "C" void kernel_launch(void* const* d_in, const int* in_sizes, int n_in,
                              void* d_out, int out_size, void* d_ws,
                              size_t ws_size, hipStream_t stream) {
  const float* buf = (const float*)d_in[0];
  const float* Wl = (const float*)d_in[1];
  const float* Wr = (const float*)d_in[2];
  const float* bias = (const float*)d_in[3];
  const int* trans = (const int*)d_in[4];
  float* out = (float*)d_out;

  const size_t gbytes = (size_t)kB * kL * kD * sizeof(float);
  if (ws_size >= gbytes) {
    float* G = (float*)d_ws;
    precomp_wr_kernel<<<dim3(kB * kL / kRowsPerBlk), dim3(128), 0, stream>>>(
        buf, Wr, G);
    spinn_kernel<true><<<dim3(kB), dim3(128), 0, stream>>>(buf, Wl, Wr, bias,
                                                           trans, G, out);
  } else {
    spinn_kernel<false><<<dim3(kB), dim3(128), 0, stream>>>(
        buf, Wl, Wr, bias, trans, nullptr, out);
  }
}

// Round 14
// 165.446 us; speedup vs baseline: 1.6626x; 1.0021x over previous
//
#include <hip/hip_runtime.h>
#include <math.h>

// SPINN thin-stack encoder, B=64, L=128, D=128, T=255.
// Phase A (parallel): G[b,l,:] = buf[b,l,:] @ Wr  for every token.
// Phase B (sequential, 1 block/example, 128 thr = 2 waves, 1 col/lane).
//   THIS ROUND'S SINGLE CHANGE vs R10 (101.5us, VGPR=132): after loading
//   the 128 Wl-column weights, each is passed through an empty
//   asm volatile("" : "+v"(w)) -- rematerialization of the load becomes
//   ILLEGAL, so the values must stay register-resident. Evidence: R10's
//   named scalars left VGPR_Count at 132 (impossible if 128 weights were
//   live) and R9 showed time scales with per-lane weight count => the
//   compiler re-loads weights from L2 every reduce step.

namespace {

constexpr int kB = 64;
constexpr int kL = 128;
constexpr int kD = 128;
constexpr int kT = 2 * kL - 1;          // 255
constexpr int kTPad = 256;              // padded transitions (tail = SKIP)
constexpr int kSlots = 160;             // fresh LDS slot per reduce (127 used)
constexpr unsigned kRecZero = 0xFFFFFFFFu;
constexpr unsigned kRecTok = 0x80000000u;
constexpr unsigned kMask = 0x7FFFFFFFu;
constexpr int kRowsPerBlk = 16;

// ---------------------------------------------------------------------------
// Phase A: G = buf @ Wr.  grid = B*L/kRowsPerBlk x 128 threads.
// ---------------------------------------------------------------------------
__global__ __launch_bounds__(128, 1) void precomp_wr_kernel(
    const float* __restrict__ buf, const float* __restrict__ Wr,
    float* __restrict__ G) {
  __shared__ float rows[kRowsPerBlk][kD];
  const int d = threadIdx.x;
  const long row0 = (long)blockIdx.x * kRowsPerBlk;

  float w[kD];
#pragma unroll
  for (int k = 0; k < kD; ++k) w[k] = Wr[k * kD + d];

  const float* src = buf + row0 * kD;
#pragma unroll
  for (int i = 0; i < kRowsPerBlk; ++i) rows[i][d] = src[i * kD + d];
  __syncthreads();

#pragma unroll
  for (int r = 0; r < kRowsPerBlk; ++r) {
    float a0 = 0.f, a1 = 0.f, a2 = 0.f, a3 = 0.f;
#pragma unroll
    for (int k4 = 0; k4 < kD / 4; ++k4) {
      const float4 x = *reinterpret_cast<const float4*>(&rows[r][k4 * 4]);
      a0 = fmaf(x.x, w[k4 * 4 + 0], a0);
      a1 = fmaf(x.y, w[k4 * 4 + 1], a1);
      a2 = fmaf(x.z, w[k4 * 4 + 2], a2);
      a3 = fmaf(x.w, w[k4 * 4 + 3], a3);
    }
    G[(row0 + r) * kD + d] = (a0 + a1) + (a2 + a3);
  }
}

__device__ __forceinline__ float fast_tanh(float x) {
  // tanh(x) = 1 - 2*rcp(e^{2x}+1)
  const float e = __expf(2.0f * x);
  return 1.0f - 2.0f * __builtin_amdgcn_rcpf(e + 1.0f);
}

// ---- 128 named weight scalars, 16 groups of 8 -----------------------------
#define DEF_WGRP(g)                                                          \
  float w_##g##_0 = Wl[((g)*8 + 0) * kD + d];                                \
  float w_##g##_1 = Wl[((g)*8 + 1) * kD + d];                                \
  float w_##g##_2 = Wl[((g)*8 + 2) * kD + d];                                \
  float w_##g##_3 = Wl[((g)*8 + 3) * kD + d];                                \
  float w_##g##_4 = Wl[((g)*8 + 4) * kD + d];                                \
  float w_##g##_5 = Wl[((g)*8 + 5) * kD + d];                                \
  float w_##g##_6 = Wl[((g)*8 + 6) * kD + d];                                \
  float w_##g##_7 = Wl[((g)*8 + 7) * kD + d];

// Opaque-ify: remat of the load is now illegal; values must stay in regs.
#define PIN_WGRP(g)                                                          \
  asm volatile("" : "+v"(w_##g##_0), "+v"(w_##g##_1), "+v"(w_##g##_2),       \
                    "+v"(w_##g##_3), "+v"(w_##g##_4), "+v"(w_##g##_5),       \
                    "+v"(w_##g##_6), "+v"(w_##g##_7));

#define FMA_GRP(g, xa, xb)                                                   \
  l0 = fmaf((xa).x, w_##g##_0, l0);                                          \
  l1 = fmaf((xa).y, w_##g##_1, l1);                                          \
  l2 = fmaf((xa).z, w_##g##_2, l2);                                          \
  l3 = fmaf((xa).w, w_##g##_3, l3);                                          \
  l4 = fmaf((xb).x, w_##g##_4, l4);                                          \
  l5 = fmaf((xb).y, w_##g##_5, l5);                                          \
  l6 = fmaf((xb).z, w_##g##_6, l6);                                          \
  l7 = fmaf((xb).w, w_##g##_7, l7);

#define LEFT_GLOBAL_GRP(g)                                                   \
  {                                                                          \
    const float4 xa = *reinterpret_cast<const float4*>(v + (g)*8);           \
    const float4 xb = *reinterpret_cast<const float4*>(v + (g)*8 + 4);       \
    FMA_GRP(g, xa, xb)                                                       \
  }

#define LEFT_LDS_GRP(g)                                                      \
  {                                                                          \
    const float4 xa = *reinterpret_cast<const float4*>(&stk[row][(g)*8]);    \
    const float4 xb = *reinterpret_cast<const float4*>(&stk[row][(g)*8 + 4]);\
    FMA_GRP(g, xa, xb)                                                       \
  }

#define ALL16(M) \
  M(0) M(1) M(2) M(3) M(4) M(5) M(6) M(7) \
  M(8) M(9) M(10) M(11) M(12) M(13) M(14) M(15)

// ---------------------------------------------------------------------------
// Phase B: grid = 64 blocks x 128 threads (2 waves). Lane d -> column d.
// LDS: gl (64KB) staged G rows; stk (80KB) composed vectors (fresh slot per
// reduce); tlds transitions; deep = record mirror (replicated writes).
// Records: kRecZero | (kRecTok|tokidx) | composed slot index.
// ---------------------------------------------------------------------------
template <bool USE_G>
__global__ __launch_bounds__(128, 1) void spinn_kernel(
    const float* __restrict__ buf, const float* __restrict__ Wl,
    const float* __restrict__ Wr, const float* __restrict__ bias,
    const int* __restrict__ trans, const float* __restrict__ G,
    float* __restrict__ out) {
  __shared__ float gl[kL][kD];        // 65536 B
  __shared__ float stk[kSlots][kD];   // 81920 B
  __shared__ int tlds[kTPad];         // 1024 B
  __shared__ unsigned deep[kT + 8];   // record mirror

  const int b = blockIdx.x;
  const int d = threadIdx.x;

  // 128 weight scalars, then PIN them (remat now illegal -> registers).
  ALL16(DEF_WGRP)
  ALL16(PIN_WGRP)
  const float bv = bias[d];

  for (int t = d; t < kTPad; t += 128) tlds[t] = (t < kT) ? trans[b * kT + t] : 2;
  deep[0] = kRecZero;
  deep[1] = kRecZero;

  const float* bufb = buf + (long)b * kL * kD;

  // Stage this example's G into LDS (64 KB, coalesced float4).
  if (USE_G) {
    const float4* g4 = reinterpret_cast<const float4*>(G + (long)b * kL * kD);
    float4* l4p = reinterpret_cast<float4*>(&gl[0][0]);
#pragma unroll
    for (int i = 0; i < (kL * kD / 4) / 128; ++i) l4p[i * 128 + d] = g4[i * 128 + d];
  }
  __syncthreads();

  unsigned r0 = kRecZero, r1 = kRecZero, r2 = kRecZero;
  int sp = 2, bp = 0, nxt = 0;

  int4 cur = *reinterpret_cast<const int4*>(&tlds[0]);
  for (int c = 0; c < kTPad / 4; ++c) {
    int4 nxtv;  // prefetch next transition chunk
    if (c < kTPad / 4 - 1)
      nxtv = *reinterpret_cast<const int4*>(&tlds[(c + 1) * 4]);
    else
      nxtv = make_int4(2, 2, 2, 2);

    const int trs[4] = {cur.x, cur.y, cur.z, cur.w};
#pragma unroll
    for (int j = 0; j < 4; ++j) {
      const int tr = trs[j];
      if (tr == 0) {
        // ---- SHIFT: record bookkeeping only ----
        const unsigned tokRec = kRecTok | (unsigned)min(bp, kL - 1);
        deep[sp] = tokRec;
        r2 = r1;
        r1 = r0;
        r0 = tokRec;
        ++sp;
        ++bp;
      } else if (tr == 1) {
        // ---- REDUCE ----
        const unsigned refill = deep[max(sp - 4, 0)];  // early refill

        float acc = bv;

        // Right operand = r0 (top). Hot: token -> LDS-staged G row.
        if (__builtin_expect(r0 != kRecZero, 1)) {
          if (__builtin_expect((r0 & kRecTok) != 0, 1)) {
            const int tok = (int)(r0 & kMask);
            if (USE_G) {
              acc += gl[tok][d];
            } else {
              const float* __restrict__ vv = bufb + (long)tok * kD;
              for (int k = 0; k < kD; ++k)
                acc = fmaf(vv[k], Wr[k * kD + d], acc);
            }
          } else {  // cold: composed right
            const int row = (int)r0;
            for (int k = 0; k < kD; ++k)
              acc = fmaf(stk[row][k], Wr[k * kD + d], acc);
          }
        }

        // Left operand = r1: the recurrence. 8 acc chains, pinned weights,
        // address-space-clean paths (no flat loads).
        float l0 = 0.f, l1 = 0.f, l2 = 0.f, l3 = 0.f;
        float l4 = 0.f, l5 = 0.f, l6 = 0.f, l7 = 0.f;
        if (__builtin_expect(r1 != kRecZero, 1)) {
          if (r1 & kRecTok) {
            const float* __restrict__ v = bufb + (long)(r1 & kMask) * kD;
            ALL16(LEFT_GLOBAL_GRP)
          } else {
            const int row = (int)r1;
            ALL16(LEFT_LDS_GRP)
          }
        }
        acc += (((l0 + l1) + (l2 + l3)) + ((l4 + l5) + (l6 + l7)));

        const float y = fast_tanh(acc);

        const int slot = nxt;  // fresh slot; never aliases a live read
        ++nxt;
        if (nxt == kSlots) nxt = 0;
        stk[slot][d] = y;

        deep[sp - 2] = (unsigned)slot;
        --sp;
        r0 = (unsigned)slot;
        r1 = r2;
        r2 = refill;
        __syncthreads();  // publish stk[slot] across the 2 waves
      }
      // tr == 2 (SKIP): no-op.
    }
    cur = nxtv;
  }

  float o = 0.f;
  if (r0 != kRecZero) {
    if (r0 & kRecTok)
      o = bufb[(long)(r0 & kMask) * kD + d];
    else
      o = stk[(int)r0][d];
  }
  out[(long)b * kD + d] = o;
}

}  // namespace

extern "C" void kernel_launch(void* const* d_in, const int* in_sizes, int n_in,
                              void* d_out, int out_size, void* d_ws,
                              size_t ws_size, hipStream_t stream) {
  const float* buf = (const float*)d_in[0];
  const float* Wl = (const float*)d_in[1];
  const float* Wr = (const float*)d_in[2];
  const float* bias = (const float*)d_in[3];
  const int* trans = (const int*)d_in[4];
  float* out = (float*)d_out;

  const size_t gbytes = (size_t)kB * kL * kD * sizeof(float);
  if (ws_size >= gbytes) {
    float* G = (float*)d_ws;
    precomp_wr_kernel<<<dim3(kB * kL / kRowsPerBlk), dim3(128), 0, stream>>>(
        buf, Wr, G);
    spinn_kernel<true><<<dim3(kB), dim3(128), 0, stream>>>(buf, Wl, Wr, bias,
                                                           trans, G, out);
  } else {
    spinn_kernel<false><<<dim3(kB), dim3(128), 0, stream>>>(
        buf, Wl, Wr, bias, trans, nullptr, out);
  }
}